// Round 8
// baseline (374.224 us; speedup 1.0000x reference)
//
#include <hip/hip_runtime.h>
#include <hip/hip_fp16.h>
#include <cmath>

typedef _Float16 f16;
typedef _Float16 f16x8 __attribute__((ext_vector_type(8)));
typedef float f32x4 __attribute__((ext_vector_type(4)));

#define B_ 128
#define N_ 512
#define H_ 64
#define K_ 16

__device__ __forceinline__ float elu_(float x) { return x > 0.f ? x : (__expf(x) - 1.f); }
__device__ __forceinline__ unsigned umin_(unsigned a, unsigned b) { return a < b ? a : b; }
__device__ __forceinline__ unsigned umax_(unsigned a, unsigned b) { return a > b ? a : b; }
__device__ __forceinline__ f32x4 mfma16(f16x8 a, f16x8 b, f32x4 c) {
    return __builtin_amdgcn_mfma_f32_16x16x32_f16(a, b, c, 0, 0, 0);
}
__device__ __forceinline__ f32x4 splat4(float v) { f32x4 r; r[0]=v; r[1]=v; r[2]=v; r[3]=v; return r; }
__device__ __forceinline__ unsigned mbcnt_(unsigned long long mask) {
    return __builtin_amdgcn_mbcnt_hi((unsigned)(mask >> 32),
           __builtin_amdgcn_mbcnt_lo((unsigned)mask, 0u));
}
__device__ __forceinline__ f16 hexp_(f16 x) {
    __half h = *(__half*)&x; h = hexp(h); return *(f16*)&h;
}
// packed-f16 elu on 8 lanes: elu(x) = max(x,0) + exp(min(x,0)) - 1
__device__ __forceinline__ f16x8 elu8h_(f16x8 x) {
    f16x8 z; f16x8 one;
    #pragma unroll
    for (int i = 0; i < 8; ++i) { z[i] = (f16)0.f; one[i] = (f16)1.f; }
    f16x8 mx = __builtin_elementwise_max(x, z);
    f16x8 mn = __builtin_elementwise_min(x, z);
    f16x8 e;
    #pragma unroll
    for (int i = 0; i < 8; ++i) e[i] = hexp_(mn[i]);
    return mx + e - one;
}
// wave-wide max via DPP (VALU pipe, no ds_swizzle); canonical shr/bcast chain.
__device__ __forceinline__ unsigned wmax64_(unsigned v) {
    v = umax_(v, (unsigned)__builtin_amdgcn_update_dpp(0, (int)v, 0x111, 0xf, 0xf, true)); // row_shr:1
    v = umax_(v, (unsigned)__builtin_amdgcn_update_dpp(0, (int)v, 0x112, 0xf, 0xf, true)); // row_shr:2
    v = umax_(v, (unsigned)__builtin_amdgcn_update_dpp(0, (int)v, 0x114, 0xf, 0xf, true)); // row_shr:4
    v = umax_(v, (unsigned)__builtin_amdgcn_update_dpp(0, (int)v, 0x118, 0xf, 0xf, true)); // row_shr:8
    v = umax_(v, (unsigned)__builtin_amdgcn_update_dpp(0, (int)v, 0x142, 0xa, 0xf, true)); // row_bcast:15
    v = umax_(v, (unsigned)__builtin_amdgcn_update_dpp(0, (int)v, 0x143, 0xc, 0xf, true)); // row_bcast:31
    return (unsigned)__builtin_amdgcn_readlane((int)v, 63);
}
// add-reduce within each 16-lane row toward lane0 (valid in lane0 of each row)
__device__ __forceinline__ float rsum16lo_(float x) {
    x += __int_as_float(__builtin_amdgcn_update_dpp(0, __float_as_int(x), 0x101, 0xf, 0xf, true));
    x += __int_as_float(__builtin_amdgcn_update_dpp(0, __float_as_int(x), 0x102, 0xf, 0xf, true));
    x += __int_as_float(__builtin_amdgcn_update_dpp(0, __float_as_int(x), 0x104, 0xf, 0xf, true));
    x += __int_as_float(__builtin_amdgcn_update_dpp(0, __float_as_int(x), 0x108, 0xf, 0xf, true));
    return x;
}

// ---------------------------------------------------------------------------
// Fused input MLP (3 layers) + sq-norms + folded-in EdgeConv weight prep
// (blocks 0..127) + zero of the last-edge completion counters (block 128).
// grid 1024 x block 256. Value-exact (same f32->f16 rounding as before).
// ---------------------------------------------------------------------------
__global__ __launch_bounds__(256) void mlp_kernel(const float* __restrict__ x,
        const float* __restrict__ W0, const float* __restrict__ b0,
        const float* __restrict__ W1, const float* __restrict__ b1,
        const float* __restrict__ W2, const float* __restrict__ b2,
        const float* __restrict__ We0, const float* __restrict__ We1,
        f16* __restrict__ PW, f16* __restrict__ QW, f16* __restrict__ W1T,
        unsigned* __restrict__ cntbuf,
        f16* __restrict__ hout, float* __restrict__ sqout)
{
    __shared__ f16 tile[4][16*72];
    __shared__ f16 w1t[64*80];
    __shared__ f16 w2t[64*80];
    const int tid = threadIdx.x;
    const int lane = tid & 63, wid = tid >> 6;
    const int m = lane & 15, q = lane >> 4;
    const int rowbase = blockIdx.x*64 + wid*16;
    f16* tw = tile[wid];

    // ---- folded-in EdgeConv weight prep (blocks 0..127, wave 0 only) ----
    if (blockIdx.x < 128 && tid < 64) {
        const int l = blockIdx.x >> 6, k = blockIdx.x & 63;
        const float* A  = We0 + l*8192;   // [128][64]
        const float* B1 = We1 + l*4096;   // [64][64]
        const float wa = A[k*64 + tid];
        const float wb = A[(k+64)*64 + tid];
        const float w1 = B1[k*64 + tid];
        PW [l*4096 + tid*64 + k] = (f16)(wa - wb);
        QW [l*4096 + tid*64 + k] = (f16)wb;
        W1T[l*4096 + tid*64 + k] = (f16)w1;
    } else if (blockIdx.x == 128) {
        // zero last-edge completion counters (visible to edge#2: 4 dispatch
        // boundaries downstream). Re-zeroed every graph replay.
        if (tid < 128) cntbuf[tid] = 0u;
    }

    // ---- stage W1/W2 -> LDS (transposed, f16) ----
    {
        const int k  = tid >> 2;
        const int n0 = (tid & 3) << 4;
        #pragma unroll
        for (int jj = 0; jj < 4; ++jj) {
            const float4 v1 = *(const float4*)(W1 + k*64 + n0 + jj*4);
            const float4 v2 = *(const float4*)(W2 + k*64 + n0 + jj*4);
            const int nb = n0 + jj*4;
            w1t[(nb+0)*80 + k] = (f16)v1.x; w1t[(nb+1)*80 + k] = (f16)v1.y;
            w1t[(nb+2)*80 + k] = (f16)v1.z; w1t[(nb+3)*80 + k] = (f16)v1.w;
            w2t[(nb+0)*80 + k] = (f16)v2.x; w2t[(nb+1)*80 + k] = (f16)v2.y;
            w2t[(nb+2)*80 + k] = (f16)v2.z; w2t[(nb+3)*80 + k] = (f16)v2.w;
        }
    }

    // ---- layer 0: A = x (K=5 padded to 32), W0 via global (tiny) ----
    f16x8 af0, af1;
    {
        const float* xp = x + (size_t)(rowbase + m)*5;
        #pragma unroll
        for (int jj = 0; jj < 8; ++jj) { int k = q*8+jj; af0[jj] = (k < 5) ? (f16)xp[k] : (f16)0.f; }
    }
    f32x4 acc[4];
    #pragma unroll
    for (int t = 0; t < 4; ++t) {
        f16x8 bf;
        #pragma unroll
        for (int jj = 0; jj < 8; ++jj) { int k = q*8+jj; bf[jj] = (k < 5) ? (f16)W0[k*64 + t*16+m] : (f16)0.f; }
        acc[t] = splat4(b0[t*16+m]);
        acc[t] = mfma16(af0, bf, acc[t]);
    }
    #pragma unroll
    for (int t = 0; t < 4; ++t)
        #pragma unroll
        for (int r = 0; r < 4; ++r)
            tw[(q*4+r)*72 + t*16+m] = (f16)elu_(acc[t][r]);
    af0 = *(const f16x8*)(tw + m*72 + q*8);
    af1 = *(const f16x8*)(tw + m*72 + q*8 + 32);
    __syncthreads();   // w1t/w2t ready

    // ---- layer 1 (fragments from LDS) ----
    #pragma unroll
    for (int t = 0; t < 4; ++t) {
        f16x8 bfa = *(const f16x8*)(w1t + (t*16+m)*80 + q*8);
        f16x8 bfb = *(const f16x8*)(w1t + (t*16+m)*80 + q*8 + 32);
        acc[t] = splat4(b1[t*16+m]);
        acc[t] = mfma16(af0, bfa, acc[t]);
        acc[t] = mfma16(af1, bfb, acc[t]);
    }
    #pragma unroll
    for (int t = 0; t < 4; ++t)
        #pragma unroll
        for (int r = 0; r < 4; ++r)
            tw[(q*4+r)*72 + t*16+m] = (f16)elu_(acc[t][r]);
    af0 = *(const f16x8*)(tw + m*72 + q*8);
    af1 = *(const f16x8*)(tw + m*72 + q*8 + 32);

    // ---- layer 2 (fragments from LDS; + h store + sq) ----
    #pragma unroll
    for (int t = 0; t < 4; ++t) {
        f16x8 bfa = *(const f16x8*)(w2t + (t*16+m)*80 + q*8);
        f16x8 bfb = *(const f16x8*)(w2t + (t*16+m)*80 + q*8 + 32);
        acc[t] = splat4(b2[t*16+m]);
        acc[t] = mfma16(af0, bfa, acc[t]);
        acc[t] = mfma16(af1, bfb, acc[t]);
    }
    float s[4] = {0.f,0.f,0.f,0.f};
    #pragma unroll
    for (int t = 0; t < 4; ++t)
        #pragma unroll
        for (int r = 0; r < 4; ++r) {
            float v = elu_(acc[t][r]);
            hout[(size_t)(rowbase + q*4 + r)*64 + t*16 + m] = (f16)v;
            s[r] += v*v;
        }
    #pragma unroll
    for (int r = 0; r < 4; ++r) s[r] = rsum16lo_(s[r]);
    if (m == 0) {
        #pragma unroll
        for (int r = 0; r < 4; ++r) sqout[rowbase + q*4 + r] = s[r];
    }
}

// ---------------------------------------------------------------------------
// kNN: block 512, R0-proven form (binary Phase A bit-descend + DPP Phase C
// max-removal). XCD-chunked bijective swizzle; pre-transposed P/Q weights.
// grid 4096 x block 512.
// ---------------------------------------------------------------------------
__global__ __launch_bounds__(512, 8) void knn_kernel(const f16* __restrict__ hin,
        const float* __restrict__ sq, int* __restrict__ idxout,
        const f16* __restrict__ PWl, const float* __restrict__ be,
        const f16* __restrict__ QWl,
        f16* __restrict__ Pout, f16* __restrict__ Qout)
{
    __shared__ unsigned keys[16*512];      // 32768 B exactly
    const int lane = threadIdx.x & 63;
    const int wid  = threadIdx.x >> 6;     // 0..7
    const int m = lane & 15, q = lane >> 4;
    // XCD-chunked swizzle: grid 4096 = 8 * 512 exactly -> bijective.
    const int bid = ((blockIdx.x & 7) << 9) | (blockIdx.x >> 3);
    const int b  = bid >> 5;
    const int rt = bid & 31;
    const int rowbase = rt*16;
    const f16* hb = hin + (size_t)b*N_*H_;
    const float* sqb = sq + b*N_;

    f16x8 af0, af1;
    {
        const f16* Ap = hb + (size_t)(rowbase + m)*64 + q*8;
        af0 = *(const f16x8*)Ap;
        af1 = *(const f16x8*)(Ap + 32);
    }
    const int colb0 = wid*16;
    f16x8 bf0[4], bf1[4];
    float sc[4];
    #pragma unroll
    for (int cti = 0; cti < 4; ++cti) {
        const f16* Bp = hb + (size_t)(colb0 + cti*128 + m)*64 + q*8;
        bf0[cti] = *(const f16x8*)Bp;
        bf1[cti] = *(const f16x8*)(Bp + 32);
        sc[cti] = sqb[colb0 + cti*128 + m];
    }
    int base_r[4];
    #pragma unroll
    for (int r = 0; r < 4; ++r) {
        const int row = q*4 + r;
        base_r[r] = row*512 + ((colb0 + m) ^ (row << 1));
    }
    #pragma unroll
    for (int cti = 0; cti < 4; ++cti) {
        f32x4 acc = splat4(0.f);
        acc = mfma16(af0, bf0[cti], acc);
        acc = mfma16(af1, bf1[cti], acc);
        #pragma unroll
        for (int r = 0; r < 4; ++r) {
            float d = fmaf(-2.f, acc[r], sc[cti]);   // sq_i dropped: row-constant
            unsigned u = __float_as_uint(d);
            u ^= (0x80000000u | (unsigned)((int)u >> 31));   // monotone order map
            unsigned key = (u & 0xFFFFFE00u) | (unsigned)(colb0 + cti*128 + m);
            keys[base_r[r] + cti*128] = key;         // immediate offset cti*512B
        }
    }
    __syncthreads();

    unsigned kk[2][8];
    #pragma unroll
    for (int rr = 0; rr < 2; ++rr) {
        const int ri = wid*2 + rr;
        *(uint4*)&kk[rr][0] = *(const uint4*)(keys + ri*512 + lane*4);
        *(uint4*)&kk[rr][4] = *(const uint4*)(keys + ri*512 + 256 + lane*4);
    }
    unsigned* scr = keys + wid*2*512;   // wave's own dead rows

    // ---- Phase A: per-lane min8, rank-17 ballot bit-descend threshold ----
    unsigned v[2];
    #pragma unroll
    for (int rr = 0; rr < 2; ++rr) {
        unsigned mn = kk[rr][0];
        #pragma unroll
        for (int s2 = 1; s2 < 8; ++s2) mn = umin_(mn, kk[rr][s2]);
        v[rr] = mn;
    }
    unsigned T[2] = {0u,0u};
    #pragma unroll
    for (int bit = 31; bit >= 9; --bit) {
        #pragma unroll
        for (int rr = 0; rr < 2; ++rr) {
            unsigned cand = T[rr] | (1u << bit);
            int c = __popcll(__ballot(v[rr] < cand));
            T[rr] = (c < 17) ? cand : T[rr];
        }
    }
    T[0] |= 511u; T[1] |= 511u;   // >=17 keys <= T (incl self)

    // ---- Phase B: batched-ballot compact ----
    unsigned cnt[2];
    #pragma unroll
    for (int rr = 0; rr < 2; ++rr) {
        unsigned long long bal[8];
        #pragma unroll
        for (int s2 = 0; s2 < 8; ++s2) bal[s2] = __ballot(kk[rr][s2] <= T[rr]);
        unsigned base = 0;
        #pragma unroll
        for (int s2 = 0; s2 < 8; ++s2) {
            if (kk[rr][s2] <= T[rr]) {
                unsigned pos = base + mbcnt_(bal[s2]);
                if (pos < 64u) scr[rr*64 + pos] = kk[rr][s2];
            }
            base += (unsigned)__popcll(bal[s2]);
        }
        cnt[rr] = base;
    }

    // ---- Phase C: kill self, DPP max-removal of (actives-16) largest ----
    #pragma unroll
    for (int rr = 0; rr < 2; ++rr) {
        const unsigned cc_ = umin_(cnt[rr], 64u);
        const int ri = wid*2 + rr;
        const unsigned rowglob = (unsigned)(rowbase + ri);
        bool act = lane < (int)cc_;
        unsigned mv = act ? scr[rr*64 + lane] : 0u;
        if (act && (mv & 511u) == rowglob) { act = false; mv = 0u; }  // self
        int e = __popcll(__ballot(act)) - 16;
        while (e > 0) {
            unsigned mx = wmax64_(mv);
            if (mv == mx) { act = false; mv = 0u; }
            --e;
        }
        int* outp = idxout + ((size_t)b*N_ + rowglob)*K_;
        unsigned long long bal = __ballot(act);       // exactly 16 lanes
        unsigned rank = mbcnt_(bal);
        if (act) outp[rank] = (int)(mv & 511u);
    }

    // ---- fused P/Q projection AFTER selection (hides in wave overlap) ----
    {
        const int t = wid & 3;
        const int n = t*16 + m;
        f32x4 acc = (wid < 4) ? splat4(be[n]) : splat4(0.f);
        const f16* Wp = (wid < 4) ? PWl : QWl;
        #pragma unroll
        for (int cc = 0; cc < 2; ++cc) {
            const f16x8 afc = cc ? af1 : af0;
            const f16x8 bb = *(const f16x8*)(Wp + n*64 + cc*32 + q*8);
            acc = mfma16(afc, bb, acc);
        }
        f16* outp = (wid < 4) ? Pout : Qout;
        #pragma unroll
        for (int r = 0; r < 4; ++r)
            outp[((size_t)b*N_ + rowbase + q*4 + r)*64 + t*16 + m] = (f16)acc[r];
    }
}

// ---------------------------------------------------------------------------
// EdgeConv layer2 + sum aggregation. 4-node batches. grid 4096 x 256.
// LAST=0: writes h + sq for the next knn (as before).
// LAST=1 (final EdgeConv): skip the 8MB store; per-block feature-max goes to
// a PRIVATE slot maxpart[batch][rt][64] via relaxed agent atomic STORES
// (device-coherent plain stores, 256B/block — R6/R7's atomic-max RMWs ran
// memory-side at 64B/op: 262K ops = 17.5MB writes + contention = 141-198us).
// Single ACQ_REL counter RMW per block publishes; last block per batch
// acquire-reads the 32x64 partials, max-reduces, runs output MLP + softmax.
// ---------------------------------------------------------------------------
template<int LAST>
__device__ __forceinline__ void edge_node_(size_t r0, f16x8 pa, f16x8 pb,
        f16x8 qa, f16x8 qb, const f16x8 (&bf)[2][4], const float (&bcol)[4],
        f16* __restrict__ out, float* __restrict__ sqout, int lane,
        float (&mxv)[4])
{
    f16x8 af0 = elu8h_(pa + qa);
    f16x8 af1 = elu8h_(pb + qb);
    f32x4 acc[4];
    #pragma unroll
    for (int t = 0; t < 4; ++t) acc[t] = splat4(bcol[t]);
    #pragma unroll
    for (int t = 0; t < 4; ++t) acc[t] = mfma16(af0, bf[0][t], acc[t]);
    #pragma unroll
    for (int t = 0; t < 4; ++t) acc[t] = mfma16(af1, bf[1][t], acc[t]);
    float ssum = 0.f;
    #pragma unroll
    for (int t = 0; t < 4; ++t) {
        float s = elu_(acc[t][0]) + elu_(acc[t][1]) + elu_(acc[t][2]) + elu_(acc[t][3]);
        s += __shfl_xor(s, 16);
        s += __shfl_xor(s, 32);
        if (LAST) {
            mxv[t] = fmaxf(mxv[t], (float)(f16)s);   // same f16 rounding as store+reload
        } else {
            if (lane < 16) out[r0*64 + t*16 + lane] = (f16)s;
            ssum += s*s;
        }
    }
    if (!LAST) {
        ssum = rsum16lo_(ssum);
        if (lane == 0) sqout[r0] = ssum;
    }
}

template<int LAST>
__global__ __launch_bounds__(256, 4) void edge_kernel(const f16* __restrict__ P,
        const f16* __restrict__ Q, const int* __restrict__ idx,
        const f16* __restrict__ W1T, const float* __restrict__ b1,
        f16* __restrict__ out, float* __restrict__ sqout,
        float* __restrict__ maxpart, unsigned* __restrict__ cntbuf,
        const float* __restrict__ Wo0, const float* __restrict__ bo0,
        const float* __restrict__ Wo1, const float* __restrict__ bo1,
        const float* __restrict__ Wo2, const float* __restrict__ bo2,
        float* __restrict__ out10)
{
    __shared__ float lred[4][64];   // cross-wave max / MLP partials
    __shared__ float gv[64];
    __shared__ float lg[10];
    __shared__ int lastflag;
    const int tid  = threadIdx.x;
    const int lane = tid & 63;
    const int wid  = tid >> 6;
    const int m = lane & 15, q = lane >> 4;

    f16x8 bf[2][4];
    #pragma unroll
    for (int cc = 0; cc < 2; ++cc)
        #pragma unroll
        for (int t = 0; t < 4; ++t)
            bf[cc][t] = *(const f16x8*)(W1T + (t*16 + m)*64 + cc*32 + q*8);
    float bcol[4];
    #pragma unroll
    for (int t = 0; t < 4; ++t) bcol[t] = b1[t*16 + m];

    // XCD-chunked swizzle (grid 4096 = 8*512, bijective)
    const int bid = ((blockIdx.x & 7) << 9) | (blockIdx.x >> 3);
    const int node0 = bid*16 + wid*4;
    const int gbase = node0 & ~(N_-1);
    const int c0a = q*8, c0b = q*8 + 32;
    int jv[4];
    #pragma unroll
    for (int i = 0; i < 4; ++i) jv[i] = idx[(size_t)(node0 + i)*K_ + m];

    f16x8 pA[4], pB[4], qA[4], qB[4];
    #pragma unroll
    for (int k2 = 0; k2 < 4; ++k2) {
        const size_t r0 = (size_t)(node0 + k2);
        const size_t g0 = (size_t)(gbase + jv[k2]);
        pA[k2] = *(const f16x8*)(P + r0*64 + c0a);
        pB[k2] = *(const f16x8*)(P + r0*64 + c0b);
        qA[k2] = *(const f16x8*)(Q + g0*64 + c0a);
        qB[k2] = *(const f16x8*)(Q + g0*64 + c0b);
    }
    float mxv[4] = {-3.0e38f, -3.0e38f, -3.0e38f, -3.0e38f};
    #pragma unroll
    for (int k2 = 0; k2 < 4; ++k2)
        edge_node_<LAST>((size_t)(node0 + k2), pA[k2], pB[k2], qA[k2], qB[k2],
                         bf, bcol, out, sqout, lane, mxv);

    if (!LAST) return;

    // ---- LAST: per-block feature-max -> private slot (coherent stores) ----
    const int bglob = bid >> 5;                   // batch of this block
    const int rt    = bid & 31;                   // block index within batch
    if (lane < 16) {
        #pragma unroll
        for (int t = 0; t < 4; ++t) lred[wid][t*16 + lane] = mxv[t];
    }
    __syncthreads();
    if (tid < 64) {
        float mm = fmaxf(fmaxf(lred[0][tid], lred[1][tid]),
                         fmaxf(lred[2][tid], lred[3][tid]));
        __hip_atomic_store(&maxpart[(bglob*32 + rt)*64 + tid], mm,
                           __ATOMIC_RELAXED, __HIP_MEMORY_SCOPE_AGENT);
    }
    __syncthreads();   // drains vmcnt: partials at coherence point
    if (tid == 0) {
        unsigned old = __hip_atomic_fetch_add(&cntbuf[bglob], 1u,
                               __ATOMIC_ACQ_REL, __HIP_MEMORY_SCOPE_AGENT);
        lastflag = (old == 31u);
    }
    __syncthreads();
    if (!lastflag) return;

    // this block finished last for batch bglob: gather partials, MLP, softmax
    if (tid < 64) {
        float mm = -3.0e38f;
        #pragma unroll 8
        for (int r2 = 0; r2 < 32; ++r2)
            mm = fmaxf(mm, __hip_atomic_load(&maxpart[(bglob*32 + r2)*64 + tid],
                           __ATOMIC_RELAXED, __HIP_MEMORY_SCOPE_AGENT));
        gv[tid] = mm;
    }
    __syncthreads();
    const int j = tid & 63, p = tid >> 6;
    {
        float a = 0.f;
        #pragma unroll
        for (int c = 0; c < 16; ++c) a += gv[p*16 + c] * Wo0[(p*16 + c)*64 + j];
        lred[p][j] = a;
    }
    __syncthreads();
    if (tid < 64) {
        float a = bo0[tid] + lred[0][tid] + lred[1][tid] + lred[2][tid] + lred[3][tid];
        gv[tid] = elu_(a);
    }
    __syncthreads();
    {
        float a = 0.f;
        #pragma unroll
        for (int c = 0; c < 16; ++c) a += gv[p*16 + c] * Wo1[(p*16 + c)*64 + j];
        lred[p][j] = a;
    }
    __syncthreads();
    if (tid < 64) {
        float a = bo1[tid] + lred[0][tid] + lred[1][tid] + lred[2][tid] + lred[3][tid];
        gv[tid] = elu_(a);
    }
    __syncthreads();
    if (tid < 10) {
        float a = bo2[tid];
        #pragma unroll
        for (int c = 0; c < 64; ++c) a += gv[c]*Wo2[c*10 + tid];
        lg[tid] = a;
    }
    __syncthreads();
    if (tid == 0) {
        float mxl = lg[0];
        for (int i = 1; i < 10; ++i) mxl = fmaxf(mxl, lg[i]);
        float s = 0.f;
        for (int i = 0; i < 10; ++i) s += expf(lg[i] - mxl);
        const float lse = mxl + logf(s);
        for (int i = 0; i < 10; ++i) out10[bglob*10 + i] = lg[i] - lse;
    }
}

extern "C" void kernel_launch(void* const* d_in, const int* in_sizes, int n_in,
                              void* d_out, int out_size, void* d_ws, size_t ws_size,
                              hipStream_t stream) {
    const float* x     = (const float*)d_in[0];
    const float* W_in0 = (const float*)d_in[1];
    const float* b_in0 = (const float*)d_in[2];
    const float* W_in1 = (const float*)d_in[3];
    const float* b_in1 = (const float*)d_in[4];
    const float* W_in2 = (const float*)d_in[5];
    const float* b_in2 = (const float*)d_in[6];
    const float* W_e0  = (const float*)d_in[7];   // [2,128,64]
    const float* b_e0  = (const float*)d_in[8];   // [2,64]
    const float* W_e1  = (const float*)d_in[9];   // [2,64,64]
    const float* b_e1  = (const float*)d_in[10];  // [2,64]
    const float* Wo0   = (const float*)d_in[11];
    const float* bo0   = (const float*)d_in[12];
    const float* Wo1   = (const float*)d_in[13];
    const float* bo1   = (const float*)d_in[14];
    const float* Wo2   = (const float*)d_in[15];
    const float* bo2   = (const float*)d_in[16];

    char* ws = (char*)d_ws;
    f16*      hA   = (f16*)(ws);                    // 8 MB
    f16*      hB   = (f16*)(ws + 8388608);          // 8 MB
    f16*      Pb   = (f16*)(ws + 16777216);         // 8 MB
    f16*      Qb   = (f16*)(ws + 25165824);         // 8 MB
    int*      idxb = (int*)(ws + 33554432);         // 4 MB
    float*    sqb  = (float*)(ws + 37748736);       // 256 KB
    f16*      PW   = (f16*)(ws + 38010880);         // 16 KB  [2][64][64]
    f16*      QW   = (f16*)(ws + 38027264);         // 16 KB  [2][64][64]
    f16*      W1T  = (f16*)(ws + 38043648);         // 16 KB  [2][64][64]
    float*    mxp  = (float*)(ws + 38060032);       // 1 MB   [128][32][64]
    unsigned* cntb = (unsigned*)(ws + 39108608);    // 512 B  [128]

    // fused input MLP + sq + weight prep + counter zeroing
    mlp_kernel<<<1024, 256, 0, stream>>>(x, W_in0, b_in0, W_in1, b_in1, W_in2, b_in2,
                                         W_e0, W_e1, PW, QW, W1T, cntb, hA, sqb);
    // block 0 (knn fuses P0/Q0)
    knn_kernel<<<4096, 512, 0, stream>>>(hA, sqb, idxb, PW, b_e0, QW, Pb, Qb);
    edge_kernel<0><<<4096, 256, 0, stream>>>(Pb, Qb, idxb, W1T, b_e1, hB, sqb,
                                             nullptr, nullptr, nullptr, nullptr,
                                             nullptr, nullptr, nullptr, nullptr, nullptr);
    // block 1 (knn fuses P1/Q1; edge fuses max-pool + output MLP + softmax)
    knn_kernel<<<4096, 512, 0, stream>>>(hB, sqb, idxb, PW + 4096, b_e0 + 64, QW + 4096, Pb, Qb);
    edge_kernel<1><<<4096, 256, 0, stream>>>(Pb, Qb, idxb, W1T + 4096, b_e1 + 64, hA, sqb,
                                             mxp, cntb, Wo0, bo0, Wo1, bo1, Wo2, bo2,
                                             (float*)d_out);
}

// Round 9
// 288.862 us; speedup vs baseline: 1.2955x; 1.2955x over previous
//
#include <hip/hip_runtime.h>
#include <hip/hip_fp16.h>
#include <cmath>

typedef _Float16 f16;
typedef _Float16 f16x8 __attribute__((ext_vector_type(8)));
typedef float f32x4 __attribute__((ext_vector_type(4)));

#define B_ 128
#define N_ 512
#define H_ 64
#define K_ 16

__device__ __forceinline__ float elu_(float x) { return x > 0.f ? x : (__expf(x) - 1.f); }
__device__ __forceinline__ unsigned umin_(unsigned a, unsigned b) { return a < b ? a : b; }
__device__ __forceinline__ unsigned umax_(unsigned a, unsigned b) { return a > b ? a : b; }
__device__ __forceinline__ f32x4 mfma16(f16x8 a, f16x8 b, f32x4 c) {
    return __builtin_amdgcn_mfma_f32_16x16x32_f16(a, b, c, 0, 0, 0);
}
__device__ __forceinline__ f32x4 splat4(float v) { f32x4 r; r[0]=v; r[1]=v; r[2]=v; r[3]=v; return r; }
__device__ __forceinline__ unsigned mbcnt_(unsigned long long mask) {
    return __builtin_amdgcn_mbcnt_hi((unsigned)(mask >> 32),
           __builtin_amdgcn_mbcnt_lo((unsigned)mask, 0u));
}
__device__ __forceinline__ f16 hexp_(f16 x) {
    __half h = *(__half*)&x; h = hexp(h); return *(f16*)&h;
}
// packed-f16 elu on 8 lanes: elu(x) = max(x,0) + exp(min(x,0)) - 1
__device__ __forceinline__ f16x8 elu8h_(f16x8 x) {
    f16x8 z; f16x8 one;
    #pragma unroll
    for (int i = 0; i < 8; ++i) { z[i] = (f16)0.f; one[i] = (f16)1.f; }
    f16x8 mx = __builtin_elementwise_max(x, z);
    f16x8 mn = __builtin_elementwise_min(x, z);
    f16x8 e;
    #pragma unroll
    for (int i = 0; i < 8; ++i) e[i] = hexp_(mn[i]);
    return mx + e - one;
}
// wave-wide max via DPP (VALU pipe, no ds_swizzle); canonical shr/bcast chain.
__device__ __forceinline__ unsigned wmax64_(unsigned v) {
    v = umax_(v, (unsigned)__builtin_amdgcn_update_dpp(0, (int)v, 0x111, 0xf, 0xf, true)); // row_shr:1
    v = umax_(v, (unsigned)__builtin_amdgcn_update_dpp(0, (int)v, 0x112, 0xf, 0xf, true)); // row_shr:2
    v = umax_(v, (unsigned)__builtin_amdgcn_update_dpp(0, (int)v, 0x114, 0xf, 0xf, true)); // row_shr:4
    v = umax_(v, (unsigned)__builtin_amdgcn_update_dpp(0, (int)v, 0x118, 0xf, 0xf, true)); // row_shr:8
    v = umax_(v, (unsigned)__builtin_amdgcn_update_dpp(0, (int)v, 0x142, 0xa, 0xf, true)); // row_bcast:15
    v = umax_(v, (unsigned)__builtin_amdgcn_update_dpp(0, (int)v, 0x143, 0xc, 0xf, true)); // row_bcast:31
    return (unsigned)__builtin_amdgcn_readlane((int)v, 63);
}
// add-reduce within each 16-lane row toward lane0 (valid in lane0 of each row)
__device__ __forceinline__ float rsum16lo_(float x) {
    x += __int_as_float(__builtin_amdgcn_update_dpp(0, __float_as_int(x), 0x101, 0xf, 0xf, true));
    x += __int_as_float(__builtin_amdgcn_update_dpp(0, __float_as_int(x), 0x102, 0xf, 0xf, true));
    x += __int_as_float(__builtin_amdgcn_update_dpp(0, __float_as_int(x), 0x104, 0xf, 0xf, true));
    x += __int_as_float(__builtin_amdgcn_update_dpp(0, __float_as_int(x), 0x108, 0xf, 0xf, true));
    return x;
}

// ---------------------------------------------------------------------------
// Fused input MLP (3 layers) + sq-norms + folded-in EdgeConv weight prep
// (blocks 0..127, first wave each — hidden under the other blocks).
// grid 1024 x block 256. Value-exact (same f32->f16 rounding as before).
// ---------------------------------------------------------------------------
__global__ __launch_bounds__(256) void mlp_kernel(const float* __restrict__ x,
        const float* __restrict__ W0, const float* __restrict__ b0,
        const float* __restrict__ W1, const float* __restrict__ b1,
        const float* __restrict__ W2, const float* __restrict__ b2,
        const float* __restrict__ We0, const float* __restrict__ We1,
        f16* __restrict__ PW, f16* __restrict__ QW, f16* __restrict__ W1T,
        f16* __restrict__ hout, float* __restrict__ sqout)
{
    __shared__ f16 tile[4][16*72];
    __shared__ f16 w1t[64*80];
    __shared__ f16 w2t[64*80];
    const int tid = threadIdx.x;
    const int lane = tid & 63, wid = tid >> 6;
    const int m = lane & 15, q = lane >> 4;
    const int rowbase = blockIdx.x*64 + wid*16;
    f16* tw = tile[wid];

    // ---- folded-in EdgeConv weight prep (blocks 0..127, wave 0 only) ----
    if (blockIdx.x < 128 && tid < 64) {
        const int l = blockIdx.x >> 6, k = blockIdx.x & 63;
        const float* A  = We0 + l*8192;   // [128][64]
        const float* B1 = We1 + l*4096;   // [64][64]
        const float wa = A[k*64 + tid];
        const float wb = A[(k+64)*64 + tid];
        const float w1 = B1[k*64 + tid];
        PW [l*4096 + tid*64 + k] = (f16)(wa - wb);
        QW [l*4096 + tid*64 + k] = (f16)wb;
        W1T[l*4096 + tid*64 + k] = (f16)w1;
    }

    // ---- stage W1/W2 -> LDS (transposed, f16) ----
    {
        const int k  = tid >> 2;
        const int n0 = (tid & 3) << 4;
        #pragma unroll
        for (int jj = 0; jj < 4; ++jj) {
            const float4 v1 = *(const float4*)(W1 + k*64 + n0 + jj*4);
            const float4 v2 = *(const float4*)(W2 + k*64 + n0 + jj*4);
            const int nb = n0 + jj*4;
            w1t[(nb+0)*80 + k] = (f16)v1.x; w1t[(nb+1)*80 + k] = (f16)v1.y;
            w1t[(nb+2)*80 + k] = (f16)v1.z; w1t[(nb+3)*80 + k] = (f16)v1.w;
            w2t[(nb+0)*80 + k] = (f16)v2.x; w2t[(nb+1)*80 + k] = (f16)v2.y;
            w2t[(nb+2)*80 + k] = (f16)v2.z; w2t[(nb+3)*80 + k] = (f16)v2.w;
        }
    }

    // ---- layer 0: A = x (K=5 padded to 32), W0 via global (tiny) ----
    f16x8 af0, af1;
    {
        const float* xp = x + (size_t)(rowbase + m)*5;
        #pragma unroll
        for (int jj = 0; jj < 8; ++jj) { int k = q*8+jj; af0[jj] = (k < 5) ? (f16)xp[k] : (f16)0.f; }
    }
    f32x4 acc[4];
    #pragma unroll
    for (int t = 0; t < 4; ++t) {
        f16x8 bf;
        #pragma unroll
        for (int jj = 0; jj < 8; ++jj) { int k = q*8+jj; bf[jj] = (k < 5) ? (f16)W0[k*64 + t*16+m] : (f16)0.f; }
        acc[t] = splat4(b0[t*16+m]);
        acc[t] = mfma16(af0, bf, acc[t]);
    }
    #pragma unroll
    for (int t = 0; t < 4; ++t)
        #pragma unroll
        for (int r = 0; r < 4; ++r)
            tw[(q*4+r)*72 + t*16+m] = (f16)elu_(acc[t][r]);
    af0 = *(const f16x8*)(tw + m*72 + q*8);
    af1 = *(const f16x8*)(tw + m*72 + q*8 + 32);
    __syncthreads();   // w1t/w2t ready

    // ---- layer 1 (fragments from LDS) ----
    #pragma unroll
    for (int t = 0; t < 4; ++t) {
        f16x8 bfa = *(const f16x8*)(w1t + (t*16+m)*80 + q*8);
        f16x8 bfb = *(const f16x8*)(w1t + (t*16+m)*80 + q*8 + 32);
        acc[t] = splat4(b1[t*16+m]);
        acc[t] = mfma16(af0, bfa, acc[t]);
        acc[t] = mfma16(af1, bfb, acc[t]);
    }
    #pragma unroll
    for (int t = 0; t < 4; ++t)
        #pragma unroll
        for (int r = 0; r < 4; ++r)
            tw[(q*4+r)*72 + t*16+m] = (f16)elu_(acc[t][r]);
    af0 = *(const f16x8*)(tw + m*72 + q*8);
    af1 = *(const f16x8*)(tw + m*72 + q*8 + 32);

    // ---- layer 2 (fragments from LDS; + h store + sq) ----
    #pragma unroll
    for (int t = 0; t < 4; ++t) {
        f16x8 bfa = *(const f16x8*)(w2t + (t*16+m)*80 + q*8);
        f16x8 bfb = *(const f16x8*)(w2t + (t*16+m)*80 + q*8 + 32);
        acc[t] = splat4(b2[t*16+m]);
        acc[t] = mfma16(af0, bfa, acc[t]);
        acc[t] = mfma16(af1, bfb, acc[t]);
    }
    float s[4] = {0.f,0.f,0.f,0.f};
    #pragma unroll
    for (int t = 0; t < 4; ++t)
        #pragma unroll
        for (int r = 0; r < 4; ++r) {
            float v = elu_(acc[t][r]);
            hout[(size_t)(rowbase + q*4 + r)*64 + t*16 + m] = (f16)v;
            s[r] += v*v;
        }
    #pragma unroll
    for (int r = 0; r < 4; ++r) s[r] = rsum16lo_(s[r]);
    if (m == 0) {
        #pragma unroll
        for (int r = 0; r < 4; ++r) sqout[rowbase + q*4 + r] = s[r];
    }
}

// ---------------------------------------------------------------------------
// kNN: block 512, R0-proven form (binary Phase A bit-descend + DPP Phase C
// max-removal). XCD-chunked bijective swizzle; pre-transposed P/Q weights.
// grid 4096 x block 512.
// ---------------------------------------------------------------------------
__global__ __launch_bounds__(512, 8) void knn_kernel(const f16* __restrict__ hin,
        const float* __restrict__ sq, int* __restrict__ idxout,
        const f16* __restrict__ PWl, const float* __restrict__ be,
        const f16* __restrict__ QWl,
        f16* __restrict__ Pout, f16* __restrict__ Qout)
{
    __shared__ unsigned keys[16*512];      // 32768 B exactly
    const int lane = threadIdx.x & 63;
    const int wid  = threadIdx.x >> 6;     // 0..7
    const int m = lane & 15, q = lane >> 4;
    // XCD-chunked swizzle: grid 4096 = 8 * 512 exactly -> bijective.
    const int bid = ((blockIdx.x & 7) << 9) | (blockIdx.x >> 3);
    const int b  = bid >> 5;
    const int rt = bid & 31;
    const int rowbase = rt*16;
    const f16* hb = hin + (size_t)b*N_*H_;
    const float* sqb = sq + b*N_;

    f16x8 af0, af1;
    {
        const f16* Ap = hb + (size_t)(rowbase + m)*64 + q*8;
        af0 = *(const f16x8*)Ap;
        af1 = *(const f16x8*)(Ap + 32);
    }
    const int colb0 = wid*16;
    f16x8 bf0[4], bf1[4];
    float sc[4];
    #pragma unroll
    for (int cti = 0; cti < 4; ++cti) {
        const f16* Bp = hb + (size_t)(colb0 + cti*128 + m)*64 + q*8;
        bf0[cti] = *(const f16x8*)Bp;
        bf1[cti] = *(const f16x8*)(Bp + 32);
        sc[cti] = sqb[colb0 + cti*128 + m];
    }
    int base_r[4];
    #pragma unroll
    for (int r = 0; r < 4; ++r) {
        const int row = q*4 + r;
        base_r[r] = row*512 + ((colb0 + m) ^ (row << 1));
    }
    #pragma unroll
    for (int cti = 0; cti < 4; ++cti) {
        f32x4 acc = splat4(0.f);
        acc = mfma16(af0, bf0[cti], acc);
        acc = mfma16(af1, bf1[cti], acc);
        #pragma unroll
        for (int r = 0; r < 4; ++r) {
            float d = fmaf(-2.f, acc[r], sc[cti]);   // sq_i dropped: row-constant
            unsigned u = __float_as_uint(d);
            u ^= (0x80000000u | (unsigned)((int)u >> 31));   // monotone order map
            unsigned key = (u & 0xFFFFFE00u) | (unsigned)(colb0 + cti*128 + m);
            keys[base_r[r] + cti*128] = key;         // immediate offset cti*512B
        }
    }
    __syncthreads();

    unsigned kk[2][8];
    #pragma unroll
    for (int rr = 0; rr < 2; ++rr) {
        const int ri = wid*2 + rr;
        *(uint4*)&kk[rr][0] = *(const uint4*)(keys + ri*512 + lane*4);
        *(uint4*)&kk[rr][4] = *(const uint4*)(keys + ri*512 + 256 + lane*4);
    }
    unsigned* scr = keys + wid*2*512;   // wave's own dead rows

    // ---- Phase A: per-lane min8, rank-17 ballot bit-descend threshold ----
    unsigned v[2];
    #pragma unroll
    for (int rr = 0; rr < 2; ++rr) {
        unsigned mn = kk[rr][0];
        #pragma unroll
        for (int s2 = 1; s2 < 8; ++s2) mn = umin_(mn, kk[rr][s2]);
        v[rr] = mn;
    }
    unsigned T[2] = {0u,0u};
    #pragma unroll
    for (int bit = 31; bit >= 9; --bit) {
        #pragma unroll
        for (int rr = 0; rr < 2; ++rr) {
            unsigned cand = T[rr] | (1u << bit);
            int c = __popcll(__ballot(v[rr] < cand));
            T[rr] = (c < 17) ? cand : T[rr];
        }
    }
    T[0] |= 511u; T[1] |= 511u;   // >=17 keys <= T (incl self)

    // ---- Phase B: batched-ballot compact ----
    unsigned cnt[2];
    #pragma unroll
    for (int rr = 0; rr < 2; ++rr) {
        unsigned long long bal[8];
        #pragma unroll
        for (int s2 = 0; s2 < 8; ++s2) bal[s2] = __ballot(kk[rr][s2] <= T[rr]);
        unsigned base = 0;
        #pragma unroll
        for (int s2 = 0; s2 < 8; ++s2) {
            if (kk[rr][s2] <= T[rr]) {
                unsigned pos = base + mbcnt_(bal[s2]);
                if (pos < 64u) scr[rr*64 + pos] = kk[rr][s2];
            }
            base += (unsigned)__popcll(bal[s2]);
        }
        cnt[rr] = base;
    }

    // ---- Phase C: kill self, DPP max-removal of (actives-16) largest ----
    #pragma unroll
    for (int rr = 0; rr < 2; ++rr) {
        const unsigned cc_ = umin_(cnt[rr], 64u);
        const int ri = wid*2 + rr;
        const unsigned rowglob = (unsigned)(rowbase + ri);
        bool act = lane < (int)cc_;
        unsigned mv = act ? scr[rr*64 + lane] : 0u;
        if (act && (mv & 511u) == rowglob) { act = false; mv = 0u; }  // self
        int e = __popcll(__ballot(act)) - 16;
        while (e > 0) {
            unsigned mx = wmax64_(mv);
            if (mv == mx) { act = false; mv = 0u; }
            --e;
        }
        int* outp = idxout + ((size_t)b*N_ + rowglob)*K_;
        unsigned long long bal = __ballot(act);       // exactly 16 lanes
        unsigned rank = mbcnt_(bal);
        if (act) outp[rank] = (int)(mv & 511u);
    }

    // ---- fused P/Q projection AFTER selection (hides in wave overlap) ----
    {
        const int t = wid & 3;
        const int n = t*16 + m;
        f32x4 acc = (wid < 4) ? splat4(be[n]) : splat4(0.f);
        const f16* Wp = (wid < 4) ? PWl : QWl;
        #pragma unroll
        for (int cc = 0; cc < 2; ++cc) {
            const f16x8 afc = cc ? af1 : af0;
            const f16x8 bb = *(const f16x8*)(Wp + n*64 + cc*32 + q*8);
            acc = mfma16(afc, bb, acc);
        }
        f16* outp = (wid < 4) ? Pout : Qout;
        #pragma unroll
        for (int r = 0; r < 4; ++r)
            outp[((size_t)b*N_ + rowbase + q*4 + r)*64 + t*16 + m] = (f16)acc[r];
    }
}

// ---------------------------------------------------------------------------
// EdgeConv layer2 + sum aggregation. 4-node batches. grid 4096 x 256.
// LAST=0: writes h + sq for the next knn (as before).
// LAST=1 (final EdgeConv): skip the 8MB h store; each block writes its 64
// feature-maxes with ONE plain coalesced 256B store to a private slot
// maxpart[batch][rt][64]. NO atomics: R6/R7/R8 all cost ~17.5MB of writes
// because 262144 per-lane agent-scope atomic ops (any flavor) are
// uncoalesced 64B memory-side transactions. Dispatch boundary before
// final2_kernel provides ordering/visibility (standard inter-kernel model).
// ---------------------------------------------------------------------------
template<int LAST>
__device__ __forceinline__ void edge_node_(size_t r0, f16x8 pa, f16x8 pb,
        f16x8 qa, f16x8 qb, const f16x8 (&bf)[2][4], const float (&bcol)[4],
        f16* __restrict__ out, float* __restrict__ sqout, int lane,
        float (&mxv)[4])
{
    f16x8 af0 = elu8h_(pa + qa);
    f16x8 af1 = elu8h_(pb + qb);
    f32x4 acc[4];
    #pragma unroll
    for (int t = 0; t < 4; ++t) acc[t] = splat4(bcol[t]);
    #pragma unroll
    for (int t = 0; t < 4; ++t) acc[t] = mfma16(af0, bf[0][t], acc[t]);
    #pragma unroll
    for (int t = 0; t < 4; ++t) acc[t] = mfma16(af1, bf[1][t], acc[t]);
    float ssum = 0.f;
    #pragma unroll
    for (int t = 0; t < 4; ++t) {
        float s = elu_(acc[t][0]) + elu_(acc[t][1]) + elu_(acc[t][2]) + elu_(acc[t][3]);
        s += __shfl_xor(s, 16);
        s += __shfl_xor(s, 32);
        if (LAST) {
            mxv[t] = fmaxf(mxv[t], (float)(f16)s);   // same f16 rounding as store+reload
        } else {
            if (lane < 16) out[r0*64 + t*16 + lane] = (f16)s;
            ssum += s*s;
        }
    }
    if (!LAST) {
        ssum = rsum16lo_(ssum);
        if (lane == 0) sqout[r0] = ssum;
    }
}

template<int LAST>
__global__ __launch_bounds__(256, 4) void edge_kernel(const f16* __restrict__ P,
        const f16* __restrict__ Q, const int* __restrict__ idx,
        const f16* __restrict__ W1T, const float* __restrict__ b1,
        f16* __restrict__ out, float* __restrict__ sqout,
        float* __restrict__ maxpart)
{
    __shared__ float lred[4][64];
    const int tid  = threadIdx.x;
    const int lane = tid & 63;
    const int wid  = tid >> 6;
    const int m = lane & 15, q = lane >> 4;

    f16x8 bf[2][4];
    #pragma unroll
    for (int cc = 0; cc < 2; ++cc)
        #pragma unroll
        for (int t = 0; t < 4; ++t)
            bf[cc][t] = *(const f16x8*)(W1T + (t*16 + m)*64 + cc*32 + q*8);
    float bcol[4];
    #pragma unroll
    for (int t = 0; t < 4; ++t) bcol[t] = b1[t*16 + m];

    // XCD-chunked swizzle (grid 4096 = 8*512, bijective)
    const int bid = ((blockIdx.x & 7) << 9) | (blockIdx.x >> 3);
    const int node0 = bid*16 + wid*4;
    const int gbase = node0 & ~(N_-1);
    const int c0a = q*8, c0b = q*8 + 32;
    int jv[4];
    #pragma unroll
    for (int i = 0; i < 4; ++i) jv[i] = idx[(size_t)(node0 + i)*K_ + m];

    f16x8 pA[4], pB[4], qA[4], qB[4];
    #pragma unroll
    for (int k2 = 0; k2 < 4; ++k2) {
        const size_t r0 = (size_t)(node0 + k2);
        const size_t g0 = (size_t)(gbase + jv[k2]);
        pA[k2] = *(const f16x8*)(P + r0*64 + c0a);
        pB[k2] = *(const f16x8*)(P + r0*64 + c0b);
        qA[k2] = *(const f16x8*)(Q + g0*64 + c0a);
        qB[k2] = *(const f16x8*)(Q + g0*64 + c0b);
    }
    float mxv[4] = {-3.0e38f, -3.0e38f, -3.0e38f, -3.0e38f};
    #pragma unroll
    for (int k2 = 0; k2 < 4; ++k2)
        edge_node_<LAST>((size_t)(node0 + k2), pA[k2], pB[k2], qA[k2], qB[k2],
                         bf, bcol, out, sqout, lane, mxv);

    if (!LAST) return;

    // ---- LAST: per-block feature-max -> private slot, plain stores ----
    const int bglob = bid >> 5;                   // batch of this block
    const int rt    = bid & 31;                   // block index within batch
    if (lane < 16) {
        #pragma unroll
        for (int t = 0; t < 4; ++t) lred[wid][t*16 + lane] = mxv[t];
    }
    __syncthreads();
    if (tid < 64) {
        float mm = fmaxf(fmaxf(lred[0][tid], lred[1][tid]),
                         fmaxf(lred[2][tid], lred[3][tid]));
        maxpart[(bglob*32 + rt)*64 + tid] = mm;   // one coalesced 256B store
    }
}

// ---------------------------------------------------------------------------
// Max over 32 block-partials (1MB total vs final_kernel's 8MB h read) +
// 3-layer output MLP + log_softmax. grid 128 x block 256. MLP tail identical
// (numerics) to the R6-R8 fused tail that passed.
// ---------------------------------------------------------------------------
__global__ __launch_bounds__(256) void final2_kernel(const float* __restrict__ maxpart,
        const float* __restrict__ Wo0, const float* __restrict__ bo0,
        const float* __restrict__ Wo1, const float* __restrict__ bo1,
        const float* __restrict__ Wo2, const float* __restrict__ bo2,
        float* __restrict__ out10)
{
    __shared__ float lred[4][64];
    __shared__ float gv[64];
    __shared__ float lg[10];
    const int tid = threadIdx.x;
    const int b = blockIdx.x;

    // parallel partial-max: 4 waves x 8 slices each
    {
        const int t64 = tid & 63, w4 = tid >> 6;
        float mm = -3.0e38f;
        #pragma unroll
        for (int r2 = 0; r2 < 8; ++r2)
            mm = fmaxf(mm, maxpart[(b*32 + w4*8 + r2)*64 + t64]);
        lred[w4][t64] = mm;
    }
    __syncthreads();
    if (tid < 64)
        gv[tid] = fmaxf(fmaxf(lred[0][tid], lred[1][tid]),
                        fmaxf(lred[2][tid], lred[3][tid]));
    __syncthreads();

    const int j = tid & 63, p = tid >> 6;
    {
        float a = 0.f;
        #pragma unroll
        for (int c = 0; c < 16; ++c) a += gv[p*16 + c] * Wo0[(p*16 + c)*64 + j];
        lred[p][j] = a;
    }
    __syncthreads();
    if (tid < 64) {
        float a = bo0[tid] + lred[0][tid] + lred[1][tid] + lred[2][tid] + lred[3][tid];
        gv[tid] = elu_(a);
    }
    __syncthreads();
    {
        float a = 0.f;
        #pragma unroll
        for (int c = 0; c < 16; ++c) a += gv[p*16 + c] * Wo1[(p*16 + c)*64 + j];
        lred[p][j] = a;
    }
    __syncthreads();
    if (tid < 64) {
        float a = bo1[tid] + lred[0][tid] + lred[1][tid] + lred[2][tid] + lred[3][tid];
        gv[tid] = elu_(a);
    }
    __syncthreads();
    if (tid < 10) {
        float a = bo2[tid];
        #pragma unroll
        for (int c = 0; c < 64; ++c) a += gv[c]*Wo2[c*10 + tid];
        lg[tid] = a;
    }
    __syncthreads();
    if (tid == 0) {
        float mxl = lg[0];
        for (int i = 1; i < 10; ++i) mxl = fmaxf(mxl, lg[i]);
        float s = 0.f;
        for (int i = 0; i < 10; ++i) s += expf(lg[i] - mxl);
        const float lse = mxl + logf(s);
        for (int i = 0; i < 10; ++i) out10[b*10 + i] = lg[i] - lse;
    }
}

extern "C" void kernel_launch(void* const* d_in, const int* in_sizes, int n_in,
                              void* d_out, int out_size, void* d_ws, size_t ws_size,
                              hipStream_t stream) {
    const float* x     = (const float*)d_in[0];
    const float* W_in0 = (const float*)d_in[1];
    const float* b_in0 = (const float*)d_in[2];
    const float* W_in1 = (const float*)d_in[3];
    const float* b_in1 = (const float*)d_in[4];
    const float* W_in2 = (const float*)d_in[5];
    const float* b_in2 = (const float*)d_in[6];
    const float* W_e0  = (const float*)d_in[7];   // [2,128,64]
    const float* b_e0  = (const float*)d_in[8];   // [2,64]
    const float* W_e1  = (const float*)d_in[9];   // [2,64,64]
    const float* b_e1  = (const float*)d_in[10];  // [2,64]
    const float* Wo0   = (const float*)d_in[11];
    const float* bo0   = (const float*)d_in[12];
    const float* Wo1   = (const float*)d_in[13];
    const float* bo1   = (const float*)d_in[14];
    const float* Wo2   = (const float*)d_in[15];
    const float* bo2   = (const float*)d_in[16];

    char* ws = (char*)d_ws;
    f16*      hA   = (f16*)(ws);                    // 8 MB
    f16*      hB   = (f16*)(ws + 8388608);          // 8 MB
    f16*      Pb   = (f16*)(ws + 16777216);         // 8 MB
    f16*      Qb   = (f16*)(ws + 25165824);         // 8 MB
    int*      idxb = (int*)(ws + 33554432);         // 4 MB
    float*    sqb  = (float*)(ws + 37748736);       // 256 KB
    f16*      PW   = (f16*)(ws + 38010880);         // 16 KB  [2][64][64]
    f16*      QW   = (f16*)(ws + 38027264);         // 16 KB  [2][64][64]
    f16*      W1T  = (f16*)(ws + 38043648);         // 16 KB  [2][64][64]
    float*    mxp  = (float*)(ws + 38060032);       // 1 MB   [128][32][64]

    // fused input MLP + sq + weight prep
    mlp_kernel<<<1024, 256, 0, stream>>>(x, W_in0, b_in0, W_in1, b_in1, W_in2, b_in2,
                                         W_e0, W_e1, PW, QW, W1T, hA, sqb);
    // block 0 (knn fuses P0/Q0)
    knn_kernel<<<4096, 512, 0, stream>>>(hA, sqb, idxb, PW, b_e0, QW, Pb, Qb);
    edge_kernel<0><<<4096, 256, 0, stream>>>(Pb, Qb, idxb, W1T, b_e1, hB, sqb, nullptr);
    // block 1 (knn fuses P1/Q1; edge writes per-block max partials, no h)
    knn_kernel<<<4096, 512, 0, stream>>>(hB, sqb, idxb, PW + 4096, b_e0 + 64, QW + 4096, Pb, Qb);
    edge_kernel<1><<<4096, 256, 0, stream>>>(Pb, Qb, idxb, W1T + 4096, b_e1 + 64, nullptr, nullptr, mxp);
    // tiny pool+MLP dispatch (reads 1MB of partials instead of 8MB h)
    final2_kernel<<<128, 256, 0, stream>>>(mxp, Wo0, bo0, Wo1, bo1, Wo2, bo2, (float*)d_out);
}